// Round 6
// baseline (248.881 us; speedup 1.0000x reference)
//
#include <hip/hip_runtime.h>
#include <stdint.h>

// Izhikevich neuron scan. x: [B=16, C=64, N=1024, T=32] f32, T contiguous.
// 1M independent neurons, 32-step sequential recurrence each.
//
// R3-R7 post-mortem: every variant converged to 85 us regardless of waves
// (5.8-16/CU), load path (VGPR vs global_load_lds) or wait style. Cause:
// (a) IR-level load sinking moves "prefetch" loads to their use site —
//     sched_barrier(0) only binds the MACHINE scheduler (VGPR stuck at 44
//     proved the pipeline never existed in the ISA);
// (b) every structure waited on memory ops ~0 cycles after issuing them
//     (loads waited at the next instruction; stores drained by barrier
//     semantics / gload_lds->ds_read hazards), so each tile exposed one or
//     two full loaded-system latencies -> per-wave tile period 12-25k cy.
//
// R8: age-everything pipeline, pinned with empty volatile asm.
//  - asm volatile(""::"+v"(reg)) right after each prefetch load: opaque at
//    IR AND machine level -> loads cannot sink; VGPR count is the tell.
//  - Tile order: [store i-1 results] [prefetch i+1] [ds_write i: backend
//    emits a COUNTED vmcnt wait for loads issued one full compute ago]
//    [compute i with per-group ds_read] [bpermute-pack spikes to 8 words].
//    Stores are NEVER waited (results held in regs, nothing reads them
//    back; only the implicit end-of-kernel drain).
//  - Output transpose via pk-pack + 8 ds_bpermute (R7-verified mapping):
//    8 DS ops, no LDS round-trip, stores stay full-line coalesced NT.
//  - 4 waves/block, private 9216 B LDS slices, NO barriers of any kind.
//    36864 B/block -> 4 blocks/CU, grid 1024 = exactly 4/CU, 16 waves/CU.
//
// Numerics: bit-exact f32 replication (contract off, left-assoc, literal
// spike-blend). Input transpose = R3-verified; output mapping = R7-verified.

#define T_STEPS 32
#define WV 64
#define WAVES 4
#define TPB (WV * WAVES)  // 256
#define NT 4              // tiles of 64 neurons per wave
#define ROW 36            // floats; 144 B rows, 16B-aligned, conflict-free
#define TILE_F 2048       // floats per tile (64 neurons x 32 steps) = 8 KB

typedef float vf4 __attribute__((ext_vector_type(4)));

// lgkmcnt(0), vmcnt=63, expcnt=7: order DS without draining VMEM.
#define WLGKM0 0xC07F

__global__ __launch_bounds__(TPB, 4) void izhikevich_kernel(
    const float* __restrict__ x,
    const float* __restrict__ pa,
    const float* __restrict__ pb,
    const float* __restrict__ pc,
    const float* __restrict__ pd,
    float* __restrict__ out)
{
#pragma clang fp contract(off)
    __shared__ float lds[WAVES * WV * ROW];      // 36864 B

    const int tid = threadIdx.x;
    const int t = tid & 63;                      // lane
    const int w = tid >> 6;                      // wave id
    float* __restrict__ wlds = &lds[w * WV * ROW];

    // Each wave owns NT consecutive 8 KB tiles.
    const size_t wave_base = (size_t)blockIdx.x * (WAVES * NT * (size_t)TILE_F)
                           + (size_t)w * (NT * (size_t)TILE_F);
    const float* __restrict__ xw = x + wave_base;
    float* __restrict__ ow = out + wave_base;

    const float a = pa[0];
    const float b = pb[0];
    const float c = pc[0];
    const float d = pd[0];

    const int sh = (t & 7) << 2;                 // nibble shift for output
    const int bpaddr = ((t >> 3) << 2);          // bpermute base addr (lane*4)

    // ---- Prologue: tile 0 loads (8 KB/wave), pinned into VGPRs -----------
    vf4 ch[8];
    {
        const vf4* __restrict__ xin = reinterpret_cast<const vf4*>(xw);
#pragma unroll
        for (int k = 0; k < 8; ++k) ch[k] = xin[k * WV + t];
#pragma unroll
        for (int k = 0; k < 8; ++k) asm volatile("" : "+v"(ch[k]));
    }

    unsigned nw[8];                              // prev tile's packed spikes

#pragma unroll
    for (int i = 0; i < NT; ++i) {
        // ---- A: store tile i-1 spikes (regs -> NT coalesced stores). -----
        // Nothing ever waits on these; they retire in the background.
        if (i > 0) {
            vf4* __restrict__ op =
                reinterpret_cast<vf4*>(ow + (size_t)(i - 1) * TILE_F);
#pragma unroll
            for (int kk = 0; kk < 8; ++kk) {
                const unsigned nib = (nw[kk] >> sh) & 0xFu;
                vf4 o;
                o.x = (nib & 1u) ? 1.0f : 0.0f;
                o.y = (nib & 2u) ? 1.0f : 0.0f;
                o.z = (nib & 4u) ? 1.0f : 0.0f;
                o.w = (nib & 8u) ? 1.0f : 0.0f;
                __builtin_nontemporal_store(o, op + kk * WV + t);
            }
        }
        __builtin_amdgcn_sched_barrier(0);

        // ---- B: prefetch tile i+1, PINNED so it cannot sink --------------
        vf4 chn[8];
        if (i + 1 < NT) {
            const vf4* __restrict__ xin =
                reinterpret_cast<const vf4*>(xw + (size_t)(i + 1) * TILE_F);
#pragma unroll
            for (int k = 0; k < 8; ++k) chn[k] = xin[k * WV + t];
#pragma unroll
            for (int k = 0; k < 8; ++k) asm volatile("" : "+v"(chn[k]));
        }
        __builtin_amdgcn_sched_barrier(0);

        // ---- C: transposing scatter of tile i into own LDS slice ---------
        // ch's loads are one full compute-phase old -> the backend's counted
        // vmcnt wait here is ~free. float4 #(k*64+t) = neuron k*8+(t>>3),
        // steps (t&7)*4.. (R3-verified mapping).
#pragma unroll
        for (int k = 0; k < 8; ++k) {
            const int ng = k * 8 + (t >> 3);
            const int tg = (t & 7) * 4;
            *reinterpret_cast<vf4*>(&wlds[ng * ROW + tg]) = ch[k];
        }
        __builtin_amdgcn_s_waitcnt(WLGKM0);      // DS ordered; VMEM untouched
        __builtin_amdgcn_sched_barrier(0);

        // ---- D: recurrence, reading own row per-float4 (bit-exact) -------
        float v = 0.0f, u = 0.0f;
        unsigned pk = 0u;
#pragma unroll
        for (int g = 0; g < 8; ++g) {
            const vf4 xg = *reinterpret_cast<const vf4*>(&wlds[t * ROW + g * 4]);
#pragma unroll
            for (int ii = 0; ii < 4; ++ii) {
                const float xt = xg[ii];
                // dv = 0.04*v*v + 5.0*v + 140.0 - u + x_t (left-assoc, no fma)
                const float t1 = (0.04f * v) * v;
                const float t2 = 5.0f * v;
                const float dv = (((t1 + t2) + 140.0f) - u) + xt;
                v = v + dv;                      // DT = 1.0 exact
                const float du = a * ((b * v) - u);
                u = u + du;
                const bool sb = (v >= 30.0f);
                const float spike = sb ? 1.0f : 0.0f;
                pk |= sb ? (1u << (4 * g + ii)) : 0u;
                const float oms = 1.0f - spike;
                v = (v * oms) + (c * spike);     // exact: spike in {0,1}
                u = u + (d * spike);
            }
        }

        // ---- E: transpose spikes wave-wide: 8 bpermutes of the pk word ---
        // Store slot kk*64+t needs neuron 8kk+(t>>3)'s word (R7-verified).
#pragma unroll
        for (int kk = 0; kk < 8; ++kk)
            nw[kk] = (unsigned)__builtin_amdgcn_ds_bpermute(
                (kk << 5) + bpaddr, (int)pk);
        __builtin_amdgcn_sched_barrier(0);

        // ---- F: rotate prefetch regs (pure renaming under full unroll) ---
        if (i + 1 < NT) {
#pragma unroll
            for (int k = 0; k < 8; ++k) ch[k] = chn[k];
        }
    }

    // ---- Epilogue: store last tile's spikes ------------------------------
    {
        vf4* __restrict__ op =
            reinterpret_cast<vf4*>(ow + (size_t)(NT - 1) * TILE_F);
#pragma unroll
        for (int kk = 0; kk < 8; ++kk) {
            const unsigned nib = (nw[kk] >> sh) & 0xFu;
            vf4 o;
            o.x = (nib & 1u) ? 1.0f : 0.0f;
            o.y = (nib & 2u) ? 1.0f : 0.0f;
            o.z = (nib & 4u) ? 1.0f : 0.0f;
            o.w = (nib & 8u) ? 1.0f : 0.0f;
            __builtin_nontemporal_store(o, op + kk * WV + t);
        }
    }
}

extern "C" void kernel_launch(void* const* d_in, const int* in_sizes, int n_in,
                              void* d_out, int out_size, void* d_ws, size_t ws_size,
                              hipStream_t stream) {
    const float* x  = (const float*)d_in[0];
    const float* pa = (const float*)d_in[1];
    const float* pb = (const float*)d_in[2];
    const float* pc = (const float*)d_in[3];
    const float* pd = (const float*)d_in[4];
    float* out = (float*)d_out;

    const int n_neurons = in_sizes[0] / T_STEPS;        // 1,048,576
    const int grid = n_neurons / (WAVES * NT * WV);     // 1024 (exact)

    izhikevich_kernel<<<grid, TPB, 0, stream>>>(x, pa, pb, pc, pd, out);
}

// Round 7
// 237.953 us; speedup vs baseline: 1.0459x; 1.0459x over previous
//
#include <hip/hip_runtime.h>

// Izhikevich neuron scan. x: [B=16, C=64, N=1024, T=32] f32, T contiguous.
// 1M independent neurons, 32-step sequential recurrence each.
//
// R3-R8 model (fits all five structures): per CU, tiles process SERIALLY at
// ~3.2k cycles each regardless of wave count (5.8-16/CU), rounds/wave (1-8),
// load path (VGPR vs global_load_lds) or output path (LDS vs bpermute):
//   3.2k = exposed load latency under load (~1.8k) + LDS round-trip (~0.3k)
//        + the recurrence's serial dependency chain (32 x ~28cy = ~0.9k).
// time = (tiles/CU) x 3.2k. R3: 64 x 3.2k = 204k cy = 85 us (measured).
// Cross-wave overlap contributes ~nothing (VALUBusy 18% == 600/3200 exactly).
// R8's asm pin backfired: "+v" READS the reg -> forced vmcnt wait at issue.
//
// R9: fewer, fatter rounds. Each thread owns TWO neurons, chains interleaved
// in-register (dep-FMA latency 4cy vs 2cy issue leaves a free slot -> second
// chain rides in the first chain's stall slots). Tile = 128 neurons = 16 KB;
// rounds/CU halve 64 -> 32; model predicts ~32 x 3.5k = 112k cy = ~47 us.
// If instead time stays ~85 us: the plateau is structure-invariant => hard
// memory-system ceiling for this mix; argue roofline next.
//
// Skeleton = proven R3/R5a: single-wave blocks, one tile per block, no
// prefetch, lgkm-only waits (never drain VMEM), normal coalesced stores.
//
// Numerics: bit-exact f32 replication (contract off, left-assoc, literal
// spike-blend); chains are independent neurons, each step sequence is the
// exact R3 sequence. LDS round-trip preserves bits.

#define T_STEPS 32
#define TPB 64          // one wave per block
#define NPB 128         // neurons per block (2 per thread)
#define ROW 36          // floats; 144 B rows, 16B-aligned, conflict-free
#define TILE_F (NPB * T_STEPS)   // 4096 floats = 16 KB

typedef float vf4 __attribute__((ext_vector_type(4)));

// lgkmcnt(0), vmcnt=63, expcnt=7: order DS without touching VMEM counters.
#define WLGKM0 0xC07F

__global__ __launch_bounds__(TPB) void izhikevich_kernel(
    const float* __restrict__ x,
    const float* __restrict__ pa,
    const float* __restrict__ pb,
    const float* __restrict__ pc,
    const float* __restrict__ pd,
    float* __restrict__ out)
{
#pragma clang fp contract(off)
    __shared__ float lds[NPB * ROW];            // 18432 B -> 8 blocks/CU

    const int t = threadIdx.x;
    const size_t base = (size_t)blockIdx.x * TILE_F;

    const float a = pa[0];
    const float b = pb[0];
    const float c = pc[0];
    const float d = pd[0];

    // ---- Phase 1: coalesced loads, 16 KB/wave issued back-to-back --------
    // float4 #(k*64+t) = neuron (8k + t/8), steps (t%8)*4 .. +3.
    const vf4* __restrict__ xin = reinterpret_cast<const vf4*>(x + base);
    vf4 ch[16];
#pragma unroll
    for (int k = 0; k < 16; ++k) ch[k] = xin[k * TPB + t];

    // ---- Phase 2: transposing scatter into LDS (b128, same banks as R3) --
    // Backend inserts counted vmcnt waits per use; loads age while earlier
    // ds_writes issue.
#pragma unroll
    for (int k = 0; k < 16; ++k) {
        const int ng = k * 8 + (t >> 3);
        const int tg = (t & 7) * 4;
        *reinterpret_cast<vf4*>(&lds[ng * ROW + tg]) = ch[k];
    }
    __builtin_amdgcn_s_waitcnt(WLGKM0);         // DS ordered; VMEM untouched
    __builtin_amdgcn_sched_barrier(0);          // cross-lane RAW fence

    // ---- Phase 3: two interleaved recurrence chains (rows t and t+64) ----
    float v0 = 0.0f, u0 = 0.0f;                 // neuron row t
    float v1 = 0.0f, u1 = 0.0f;                 // neuron row t+64
#pragma unroll
    for (int g = 0; g < 8; ++g) {
        const vf4 xa = *reinterpret_cast<const vf4*>(&lds[t * ROW + g * 4]);
        const vf4 xb = *reinterpret_cast<const vf4*>(&lds[(t + 64) * ROW + g * 4]);
        vf4 sa, sb;
#pragma unroll
        for (int i = 0; i < 4; ++i) {
            // chain 0 (exact R3 sequence)
            const float ta1 = (0.04f * v0) * v0;
            const float ta2 = 5.0f * v0;
            const float dva = (((ta1 + ta2) + 140.0f) - u0) + xa[i];
            v0 = v0 + dva;                       // DT = 1.0 exact
            const float dua = a * ((b * v0) - u0);
            u0 = u0 + dua;
            const float spa = (v0 >= 30.0f) ? 1.0f : 0.0f;
            const float oma = 1.0f - spa;
            v0 = (v0 * oma) + (c * spa);         // exact: spike in {0,1}
            u0 = u0 + (d * spa);
            sa[i] = spa;
            // chain 1 (independent; fills chain 0's dependency stalls)
            const float tb1 = (0.04f * v1) * v1;
            const float tb2 = 5.0f * v1;
            const float dvb = (((tb1 + tb2) + 140.0f) - u1) + xb[i];
            v1 = v1 + dvb;
            const float dub = a * ((b * v1) - u1);
            u1 = u1 + dub;
            const float spb = (v1 >= 30.0f) ? 1.0f : 0.0f;
            const float omb = 1.0f - spb;
            v1 = (v1 * omb) + (c * spb);
            u1 = u1 + (d * spb);
            sb[i] = spb;
        }
        // spikes back to own rows (same-lane MustAlias with the reads above)
        *reinterpret_cast<vf4*>(&lds[t * ROW + g * 4]) = sa;
        *reinterpret_cast<vf4*>(&lds[(t + 64) * ROW + g * 4]) = sb;
    }
    __builtin_amdgcn_s_waitcnt(WLGKM0);         // spike writes done
    __builtin_amdgcn_sched_barrier(0);          // cross-lane RAW fence

    // ---- Phase 4: inverse transpose gather + coalesced stores ------------
    // Stores are never waited on (end-of-kernel drain only).
    {
        vf4* __restrict__ op = reinterpret_cast<vf4*>(out + base);
#pragma unroll
        for (int k = 0; k < 16; ++k) {
            const int ng = k * 8 + (t >> 3);
            const int tg = (t & 7) * 4;
            const vf4 o = *reinterpret_cast<const vf4*>(&lds[ng * ROW + tg]);
            op[k * TPB + t] = o;
        }
    }
}

extern "C" void kernel_launch(void* const* d_in, const int* in_sizes, int n_in,
                              void* d_out, int out_size, void* d_ws, size_t ws_size,
                              hipStream_t stream) {
    const float* x  = (const float*)d_in[0];
    const float* pa = (const float*)d_in[1];
    const float* pb = (const float*)d_in[2];
    const float* pc = (const float*)d_in[3];
    const float* pd = (const float*)d_in[4];
    float* out = (float*)d_out;

    const int n_neurons = in_sizes[0] / T_STEPS;   // 1,048,576
    const int grid = n_neurons / NPB;              // 8192 (exact)

    izhikevich_kernel<<<grid, TPB, 0, stream>>>(x, pa, pb, pc, pd, out);
}